// Round 7
// baseline (161.032 us; speedup 1.0000x reference)
//
#include <hip/hip_runtime.h>
#include <hip/hip_bf16.h>
#include <stdint.h>

typedef __attribute__((ext_vector_type(4))) float f32x4;
typedef __attribute__((ext_vector_type(8))) short short8;
typedef __attribute__((ext_vector_type(4))) int int4v;

#define IN_F   8192
#define OUT_F  8192
#define MROWS  256
#define NGRP   128   // IN_F / 64
#define QROW   4096  // int32s per q_weight row = IN_F/2
#define KTILES 32    // k-tiles (BK=64) per block, split-K=4

// Static device scratch — no dependence on d_ws/ws_size.
__device__ unsigned short g_xb[MROWS * IN_F];        // 4 MB bf16 x, fragment-major
__device__ float          g_t[MROWS * 16];           // LoRA intermediate
__device__ float          g_part[4 * MROWS * OUT_F]; // 32 MB split-K partials

// NF4 levels: Phi^{-1}((i+0.5)/16) / Phi^{-1}(15.5/16)
__device__ __constant__ float NF4_LVL[16] = {
  -1.0f,        -0.70756721f, -0.54221982f, -0.41681853f,
  -0.31090474f, -0.21594601f, -0.12734085f, -0.04209530f,
   0.04209530f,  0.12734085f,  0.21594601f,  0.31090474f,
   0.41681853f,  0.54221982f,  0.70756721f,  1.0f };

static __device__ inline uint32_t pkbf(float a, float b) {
  __bf16 ha = (__bf16)a, hb = (__bf16)b;
  return (uint32_t)__builtin_bit_cast(unsigned short, ha)
       | ((uint32_t)__builtin_bit_cast(unsigned short, hb) << 16);
}

// ---- k0: x fp32 -> bf16, fragment-major:
// 16B-chunk d: l15=d&15, sub=(d>>4)&3, kk=(d>>6)&1, m16=(d>>7)&15, kt=d>>11
// holds x[m16*16+l15][kt*64 + (kk*4+sub)*8 .. +8].
__global__ __launch_bounds__(256) void k_convert(const float* __restrict__ x) {
  int d = blockIdx.x * 256 + threadIdx.x;   // 262144 chunks
  int l15 = d & 15, sub = (d >> 4) & 3, kk = (d >> 6) & 1;
  int m16 = (d >> 7) & 15, kt = d >> 11;
  int r = m16 * 16 + l15;
  int k = kt * 64 + (kk * 4 + sub) * 8;
  const float* src = x + (size_t)r * IN_F + k;
  f32x4 v0 = *(const f32x4*)src;
  f32x4 v1 = *(const f32x4*)(src + 4);
  int4v ov;
  ov[0] = (int)pkbf(v0.x, v0.y); ov[1] = (int)pkbf(v0.z, v0.w);
  ov[2] = (int)pkbf(v1.x, v1.y); ov[3] = (int)pkbf(v1.z, v1.w);
  *(int4v*)(g_xb + (size_t)d * 8) = ov;
}

// ---- k1: g_t = 2 * x @ lora_A^T
__global__ __launch_bounds__(256) void k_xa(const float* __restrict__ x,
                                            const float* __restrict__ lora_A) {
  int m = blockIdx.x, tid = threadIdx.x;
  float acc[16];
#pragma unroll
  for (int r = 0; r < 16; ++r) acc[r] = 0.f;
  const float* xr = x + (size_t)m * IN_F;
  for (int it = 0; it < 8; ++it) {
    int k = (tid + it * 256) * 4;
    f32x4 xv = *(const f32x4*)(xr + k);
#pragma unroll
    for (int r = 0; r < 16; ++r) {
      f32x4 av = *(const f32x4*)(lora_A + (size_t)r * IN_F + k);
      acc[r] += xv.x * av.x + xv.y * av.y + xv.z * av.z + xv.w * av.w;
    }
  }
#pragma unroll
  for (int r = 0; r < 16; ++r) {
    float v = acc[r];
#pragma unroll
    for (int off = 32; off; off >>= 1) v += __shfl_xor(v, off, 64);
    acc[r] = v;
  }
  __shared__ float sm[4][16];
  int lane = tid & 63, wave = tid >> 6;
  if (lane == 0) {
#pragma unroll
    for (int r = 0; r < 16; ++r) sm[wave][r] = acc[r];
  }
  __syncthreads();
  if (tid < 16)
    g_t[m * 16 + tid] = 2.0f * (sm[0][tid] + sm[1][tid] + sm[2][tid] + sm[3][tid]);
}

// ---- k3: main GEMM, zero-barrier all-register dataflow.
// 256 blocks (1/CU), 512 thr = 8 waves (4 M-groups x 2 N-halves), per-wave M64xN64.
// B: q int32s -> regs -> 256-entry packed-LUT dequant -> MFMA B-frags (no LDS staging).
// A: fragment-major g_xb via plain global loads (L2-resident per XCD).
__global__ __launch_bounds__(512, 2) void k_gemm(
    const int* __restrict__ qw, const float* __restrict__ scales)
{
  __shared__ uint32_t lut2[256];   // packed bf16 pair: low short = lv[hi-nibble]
  int tid = threadIdx.x;
  int lane = tid & 63, wave = tid >> 6;
  if (tid < 256) lut2[tid] = pkbf(NF4_LVL[tid >> 4], NF4_LVL[tid & 15]);
  __syncthreads();   // the only barrier in the kernel

  // XCD swizzle: each XCD's 32 blocks share one bz (1 MB g_xb slice L2-resident)
  int flat = blockIdx.x;
  int wg = (flat & 7) * 32 + (flat >> 3);
  int bx = wg & 63, bz = wg >> 6;
  int n0 = bx * 128;            // BN=128
  int ktg0 = bz * KTILES;

  int wr = wave >> 1;           // 0..3 : M group (64 rows)
  int wc = wave & 1;            // 0..1 : N half (64 cols)
  int wn = wc * 64;
  int sub = lane >> 4, l15 = lane & 15;

  // B-side: per lane, 4 q-rows (ni*16 apart); int index = ktg*32 + kk*16 + sub*4
  size_t rowb = (size_t)(n0 + wn + l15);
  const int* qbase = qw + rowb * QROW + sub * 4;
  const float* sbase = scales + rowb * NGRP;

  // A-side: frag(kt, m16, kk) at (kt*16+m16)*1024 + kk*512 ushorts
  const unsigned short* abase =
      g_xb + (size_t)ktg0 * 16384 + (wr * 4) * 1024 + (sub * 16 + l15) * 8;

  f32x4 acc[4][4];
#pragma unroll
  for (int i = 0; i < 4; ++i)
#pragma unroll
    for (int j = 0; j < 4; ++j) acc[i][j] = (f32x4){0.f, 0.f, 0.f, 0.f};

  // prefetch q/scales for tile 0
  int4v qb[8];   // [ni*2+kk]
  float sb[4];
#pragma unroll
  for (int ni = 0; ni < 4; ++ni) {
    const int* qp = qbase + (size_t)ni * 16 * QROW + (size_t)ktg0 * 32;
    qb[ni * 2 + 0] = *(const int4v*)qp;
    qb[ni * 2 + 1] = *(const int4v*)(qp + 16);
    sb[ni] = sbase[(size_t)ni * 16 * NGRP + ktg0];
  }

#pragma clang loop unroll(disable)
  for (int t = 0; t < KTILES; ++t) {
    // A fragments for this tile (8 x 16B per lane, from L2)
    short8 af[2][4];
    const unsigned short* ab = abase + (size_t)t * 16384;
#pragma unroll
    for (int kk = 0; kk < 2; ++kk)
#pragma unroll
      for (int mi = 0; mi < 4; ++mi)
        af[kk][mi] = *(const short8*)(ab + mi * 1024 + kk * 512);

    // prefetch q/scales for tile t+1 (stay in flight under this tile's work)
    int tn = (t < KTILES - 1) ? (t + 1) : t;
    size_t koff = (size_t)(ktg0 + tn) * 32;
    int4v qn[8];
    float sn[4];
#pragma unroll
    for (int ni = 0; ni < 4; ++ni) {
      const int* qp = qbase + (size_t)ni * 16 * QROW + koff;
      qn[ni * 2 + 0] = *(const int4v*)qp;
      qn[ni * 2 + 1] = *(const int4v*)(qp + 16);
      sn[ni] = sbase[(size_t)ni * 16 * NGRP + (ktg0 + tn)];
    }

    // dequant current q -> B frags (per (ni,kk): 4 ints -> 8 bf16 weights)
    short8 bq[8];   // [ni*2+kk]
#pragma unroll
    for (int ni = 0; ni < 4; ++ni) {
      float s = sb[ni];
#pragma unroll
      for (int kk = 0; kk < 2; ++kk) {
        int4v q = qb[ni * 2 + kk];
        int4v ov;
#pragma unroll
        for (int e = 0; e < 4; ++e) {
          uint32_t pk = lut2[q[e] & 255];
          float fh = __builtin_bit_cast(float, pk << 16);
          float fl = __builtin_bit_cast(float, pk & 0xFFFF0000u);
          ov[e] = (int)pkbf(fh * s, fl * s);
        }
        bq[ni * 2 + kk] = __builtin_bit_cast(short8, ov);
      }
    }
#pragma unroll
    for (int i = 0; i < 8; ++i) qb[i] = qn[i];
#pragma unroll
    for (int i = 0; i < 4; ++i) sb[i] = sn[i];

    __builtin_amdgcn_s_setprio(1);
#pragma unroll
    for (int kk = 0; kk < 2; ++kk)
#pragma unroll
      for (int mi = 0; mi < 4; ++mi)
#pragma unroll
        for (int ni = 0; ni < 4; ++ni)
          acc[mi][ni] = __builtin_amdgcn_mfma_f32_16x16x32_bf16(
              af[kk][mi], bq[ni * 2 + kk], acc[mi][ni], 0, 0, 0);
    __builtin_amdgcn_s_setprio(0);
  }

  // epilogue -> per-slice partials. D layout: col=lane&15, row=(lane>>4)*4+reg
  float* op = g_part + (size_t)bz * MROWS * OUT_F;
#pragma unroll
  for (int mi = 0; mi < 4; ++mi) {
#pragma unroll
    for (int ni = 0; ni < 4; ++ni) {
      int m = wr * 64 + mi * 16 + sub * 4;
      int nn = n0 + wn + ni * 16 + l15;
#pragma unroll
      for (int j = 0; j < 4; ++j)
        op[(size_t)(m + j) * OUT_F + nn] = acc[mi][ni][j];
    }
  }
}

// ---- k4: out = sum of 4 split-K partials + LoRA (g_t @ lora_B^T), fused
__global__ __launch_bounds__(256) void k_reduce(const float* __restrict__ lora_B,
                                                float* __restrict__ out) {
  size_t i = ((size_t)blockIdx.x * 256 + threadIdx.x) * 4;
  int m = (int)(i >> 13);
  int n = (int)(i & 8191);
  f32x4 v = *(const f32x4*)(g_part + i);
  v += *(const f32x4*)(g_part + (size_t)1 * MROWS * OUT_F + i);
  v += *(const f32x4*)(g_part + (size_t)2 * MROWS * OUT_F + i);
  v += *(const f32x4*)(g_part + (size_t)3 * MROWS * OUT_F + i);
  const float* tr = g_t + m * 16;
  f32x4 t0 = *(const f32x4*)tr,       t1 = *(const f32x4*)(tr + 4);
  f32x4 t2 = *(const f32x4*)(tr + 8), t3 = *(const f32x4*)(tr + 12);
#pragma unroll
  for (int j = 0; j < 4; ++j) {
    const float* br = lora_B + (size_t)(n + j) * 16;
    f32x4 b0 = *(const f32x4*)br,       b1 = *(const f32x4*)(br + 4);
    f32x4 b2 = *(const f32x4*)(br + 8), b3 = *(const f32x4*)(br + 12);
    v[j] += t0.x*b0.x + t0.y*b0.y + t0.z*b0.z + t0.w*b0.w
          + t1.x*b1.x + t1.y*b1.y + t1.z*b1.z + t1.w*b1.w
          + t2.x*b2.x + t2.y*b2.y + t2.z*b2.z + t2.w*b2.w
          + t3.x*b3.x + t3.y*b3.y + t3.z*b3.z + t3.w*b3.w;
  }
  *(f32x4*)(out + i) = v;
}

extern "C" void kernel_launch(void* const* d_in, const int* in_sizes, int n_in,
                              void* d_out, int out_size, void* d_ws, size_t ws_size,
                              hipStream_t stream) {
  const float* x  = (const float*)d_in[0];
  const int*   qw = (const int*)d_in[1];
  const float* sc = (const float*)d_in[2];
  const float* lA = (const float*)d_in[3];
  const float* lB = (const float*)d_in[4];
  float* out = (float*)d_out;

  k_convert<<<1024, 256, 0, stream>>>(x);
  k_xa<<<256, 256, 0, stream>>>(x, lA);
  k_gemm<<<256, 512, 0, stream>>>(qw, sc);
  k_reduce<<<2048, 256, 0, stream>>>(lB, out);
}